// Round 14
// baseline (652.349 us; speedup 1.0000x reference)
//
#include <hip/hip_runtime.h>
#include <hip/hip_fp16.h>

#define DIM 64
#define NGRAPH 128
#define GATTR 4
#define BN_EPS 1e-5f
#define SCAN_CHUNK 4096   // 256 threads x 16 elems (generic scan)
#define SCHUNK 4096       // edges per binning block
#define BUCKET_SHIFT 7
#define BUCKET 128        // nodes per bucket; nbuck = ceil(N/128)
#define XS 17             // padded A/H row stride in float4 units (68 floats)

// ---------------- small zero (gsum/gcnt only) ----------------

__global__ __launch_bounds__(256) void k_zero(float* __restrict__ gsum,
                                              int* __restrict__ gcnt) {
    int i0 = blockIdx.x * 256 + threadIdx.x;
    if (i0 < NGRAPH * DIM) gsum[i0] = 0.f;
    if (i0 < NGRAPH) gcnt[i0] = 0;
}

// ---------------- f32 -> fp16 cast for input features ----------------

__global__ __launch_bounds__(256) void k_cast(const float4* __restrict__ x4,
                                              uint2* __restrict__ o, int n4) {
    int stride = gridDim.x * 256;
    for (int i = blockIdx.x * 256 + threadIdx.x; i < n4; i += stride) {
        float4 v = x4[i];
        __half2 a = __float22half2_rn(make_float2(v.x, v.y));
        __half2 b = __float22half2_rn(make_float2(v.z, v.w));
        uint2 u;
        u.x = *(unsigned int*)&a;
        u.y = *(unsigned int*)&b;
        o[i] = u;
    }
}

// ---------------- CSR build: deterministic rank-and-place (no global atomics) ----

__global__ __launch_bounds__(256) void k_bhist(const int* __restrict__ dst,
                                               int* __restrict__ hist,
                                               int E, int nb, int nbuck) {
    __shared__ int lb[1024];
    int tid = threadIdx.x, blk = blockIdx.x;
    int base = blk * SCHUNK;
    int cnt = min(SCHUNK, E - base);
    for (int i = tid; i < nbuck; i += 256) lb[i] = 0;
    __syncthreads();
    for (int i = tid; i < cnt; i += 256)
        atomicAdd(&lb[dst[base + i] >> BUCKET_SHIFT], 1);
    __syncthreads();
    for (int b = tid; b < nbuck; b += 256) hist[b * nb + blk] = lb[b];
}

__global__ __launch_bounds__(256) void k_gscan1(const int* __restrict__ in,
                                                int* __restrict__ out,
                                                int* __restrict__ partials, int n) {
    __shared__ int ws[256];
    int tid = threadIdx.x;
    int base = blockIdx.x * SCAN_CHUNK + tid * 16;
    int v[16];
    int s = 0;
#pragma unroll
    for (int i = 0; i < 16; ++i) {
        int idx = base + i;
        v[i] = (idx < n) ? in[idx] : 0;
        s += v[i];
    }
    ws[tid] = s;
    __syncthreads();
    for (int off = 1; off < 256; off <<= 1) {
        int t = (tid >= off) ? ws[tid - off] : 0;
        __syncthreads();
        ws[tid] += t;
        __syncthreads();
    }
    int excl = (tid == 0) ? 0 : ws[tid - 1];
    if (tid == 255) partials[blockIdx.x] = ws[255];
#pragma unroll
    for (int i = 0; i < 16; ++i) {
        int idx = base + i;
        if (idx < n) out[idx] = excl;
        excl += v[i];
    }
}

__global__ __launch_bounds__(256) void k_gscan23(int* __restrict__ data,
                                                 const int* __restrict__ partials,
                                                 int n) {
    __shared__ int soff;
    if (threadIdx.x == 0) {
        int s = 0;
        for (int j = 0; j < blockIdx.x; ++j) s += partials[j];
        soff = s;
    }
    __syncthreads();
    int off = soff;
    int base = blockIdx.x * SCAN_CHUNK;
    for (int i = threadIdx.x; i < SCAN_CHUNK; i += 256) {
        int idx = base + i;
        if (idx < n) data[idx] += off;
    }
}

__global__ __launch_bounds__(256) void k_sbin(const int* __restrict__ src,
                                              const int* __restrict__ dst,
                                              const int* __restrict__ hist,
                                              int2* __restrict__ pairs,
                                              int E, int nb, int nbuck) {
    __shared__ int lhist[1024];
    __shared__ int lofs[1024];
    __shared__ int lcur[1024];
    __shared__ int lgb[1024];
    __shared__ int ws[256];
    __shared__ int2 stage[SCHUNK];  // 32 KiB
    int tid = threadIdx.x, blk = blockIdx.x;
    int base = blk * SCHUNK;
    int cnt = min(SCHUNK, E - base);

    for (int i = tid; i < nbuck; i += 256) lhist[i] = 0;
    __syncthreads();

    int2 mine[16];
    int nmine = 0;
    for (int i = tid; i < cnt; i += 256) {
        int s = src[base + i];
        int d = dst[base + i];
        mine[nmine++] = make_int2(s, d);
        atomicAdd(&lhist[d >> BUCKET_SHIFT], 1);
    }
    __syncthreads();

    {
        int b0 = tid * 4;
        int v0 = (b0 + 0 < nbuck) ? lhist[b0 + 0] : 0;
        int v1 = (b0 + 1 < nbuck) ? lhist[b0 + 1] : 0;
        int v2 = (b0 + 2 < nbuck) ? lhist[b0 + 2] : 0;
        int v3 = (b0 + 3 < nbuck) ? lhist[b0 + 3] : 0;
        int s = v0 + v1 + v2 + v3;
        ws[tid] = s;
        __syncthreads();
        for (int off = 1; off < 256; off <<= 1) {
            int t = (tid >= off) ? ws[tid - off] : 0;
            __syncthreads();
            ws[tid] += t;
            __syncthreads();
        }
        int excl = (tid == 0) ? 0 : ws[tid - 1];
        if (b0 + 0 < nbuck) lofs[b0 + 0] = excl;
        excl += v0;
        if (b0 + 1 < nbuck) lofs[b0 + 1] = excl;
        excl += v1;
        if (b0 + 2 < nbuck) lofs[b0 + 2] = excl;
        excl += v2;
        if (b0 + 3 < nbuck) lofs[b0 + 3] = excl;
    }
    __syncthreads();
    for (int b = tid; b < nbuck; b += 256) {
        lcur[b] = lofs[b];
        lgb[b] = hist[b * nb + blk];
    }
    __syncthreads();

    for (int j = 0; j < nmine; ++j) {
        int b = mine[j].y >> BUCKET_SHIFT;
        int pos = atomicAdd(&lcur[b], 1);
        stage[pos] = mine[j];
    }
    __syncthreads();

    for (int i = tid; i < cnt; i += 256) {
        int2 pr = stage[i];
        int b = pr.y >> BUCKET_SHIFT;
        pairs[lgb[b] + (i - lofs[b])] = pr;
    }
}

__global__ __launch_bounds__(256) void k_bsort(const int2* __restrict__ pairs,
                                               const int* __restrict__ hist,
                                               int* __restrict__ rowptr,
                                               int* __restrict__ col,
                                               int n, int nb, int nbuck, int E) {
    __shared__ int lcnt[BUCKET];
    __shared__ int lofs[BUCKET];
    int b = blockIdx.x;
    int tid = threadIdx.x;
    int cbase = hist[b * nb];
    int nxt = (b + 1 < nbuck) ? hist[(b + 1) * nb] : E;
    int ecnt = nxt - cbase;
    int node0 = b << BUCKET_SHIFT;
    int nn = min(BUCKET, n - node0);
    if (tid < BUCKET) lcnt[tid] = 0;
    __syncthreads();
    for (int i = tid; i < ecnt; i += 256)
        atomicAdd(&lcnt[pairs[cbase + i].y - node0], 1);
    __syncthreads();
    int v = (tid < BUCKET) ? lcnt[tid] : 0;
    if (tid < BUCKET) lofs[tid] = v;
    __syncthreads();
    for (int off = 1; off < BUCKET; off <<= 1) {
        int t = (tid < BUCKET && tid >= off) ? lofs[tid - off] : 0;
        __syncthreads();
        if (tid < BUCKET) lofs[tid] += t;
        __syncthreads();
    }
    int excl = (tid < BUCKET) ? (lofs[tid] - v) : 0;
    __syncthreads();
    if (tid < BUCKET) lofs[tid] = excl;
    if (tid < nn) rowptr[node0 + tid] = cbase + excl;
    __syncthreads();
    for (int i = tid; i < ecnt; i += 256) {
        int2 pr = pairs[cbase + i];
        int p = cbase + atomicAdd(&lofs[pr.y - node0], 1);
        col[p] = pr.x;
    }
    if (b == 0 && tid == 0) rowptr[n] = E;
}

// ---------------- fused SAGE layer: mean-agg + (A@Wl + bl + H@Wr) + BN + ReLU ----
// One 64-node tile per block, 256 threads. Phase 1: stage Wl/Wr/H-tile into LDS
// (gather doesn't read LDS -> no barrier needed before phase 2). Phase 2: each
// wave aggregates its 16 nodes with the (g,p)=8x8 gather layout, result into sA
// (node is wave-uniform -> zero divergence). Single barrier. Phase 3: proven
// 4-node x 4-dim register-tile matmul + BN + ReLU epilogue, fp16 out.

__global__ __launch_bounds__(256) void k_layer(const __half* __restrict__ h16in,
                                               const int* __restrict__ row_ptr,
                                               const int* __restrict__ col,
                                               const float* __restrict__ Wl,
                                               const float* __restrict__ bl,
                                               const float* __restrict__ Wr,
                                               const float* __restrict__ bng,
                                               const float* __restrict__ bnb,
                                               const float* __restrict__ bnm,
                                               const float* __restrict__ bnv,
                                               __half* __restrict__ out16, int n) {
    __shared__ float4 sWl[64 * 16];
    __shared__ float4 sWr[64 * 16];
    __shared__ float4 sA[64 * XS];
    __shared__ float4 sH[64 * XS];
    int tid = threadIdx.x;
    int base = blockIdx.x * 64;
    int rows = min(64, n - base);

    // ---- Phase 1: stage weights + H tile (fp16 -> f32) ----
    const float4* Wl4 = (const float4*)Wl;
    const float4* Wr4 = (const float4*)Wr;
    const uint2* H2 = (const uint2*)(h16in + (size_t)base * DIM);
    for (int i = tid; i < 1024; i += 256) {
        sWl[i] = Wl4[i];
        sWr[i] = Wr4[i];
        int row = i >> 4, c = i & 15;
        float4 vh = {0.f, 0.f, 0.f, 0.f};
        if (row < rows) {
            uint2 u = H2[i];
            const __half2* q = (const __half2*)&u;
            float2 lo = __half22float2(q[0]);
            float2 hi = __half22float2(q[1]);
            vh.x = lo.x; vh.y = lo.y; vh.z = hi.x; vh.w = hi.y;
        }
        sH[row * XS + c] = vh;
    }

    // ---- Phase 2: per-wave aggregation of 16 nodes into sA ----
    int lane = tid & 63;
    int wv = tid >> 6;
    int g = lane >> 3;   // edge slot (8)
    int p = lane & 7;    // dim oct: dims 8p..8p+7
    for (int t = 0; t < 16; ++t) {
        int nd = wv * 16 + t;
        int node = base + nd;         // wave-uniform
        int beg = 0, end = 0;
        if (node < n) { beg = row_ptr[node]; end = row_ptr[node + 1]; }

        float a0 = 0.f, a1 = 0.f, a2 = 0.f, a3 = 0.f;
        float a4 = 0.f, a5 = 0.f, a6 = 0.f, a7 = 0.f;
#define ACCUM(V)                                                          \
        {                                                                 \
            const __half2* q = (const __half2*)&(V);                      \
            float2 f0 = __half22float2(q[0]);                             \
            float2 f1 = __half22float2(q[1]);                             \
            float2 f2 = __half22float2(q[2]);                             \
            float2 f3 = __half22float2(q[3]);                             \
            a0 += f0.x; a1 += f0.y; a2 += f1.x; a3 += f1.y;               \
            a4 += f2.x; a5 += f2.y; a6 += f3.x; a7 += f3.y;               \
        }
        int j = beg + g;
        for (; j + 8 < end; j += 16) {
            int s0 = col[j];
            int s1 = col[j + 8];
            uint4 v0 = ((const uint4*)(h16in + (size_t)s0 * DIM))[p];
            uint4 v1 = ((const uint4*)(h16in + (size_t)s1 * DIM))[p];
            ACCUM(v0)
            ACCUM(v1)
        }
        if (j < end) {
            int s0 = col[j];
            uint4 v0 = ((const uint4*)(h16in + (size_t)s0 * DIM))[p];
            ACCUM(v0)
        }
#undef ACCUM
#pragma unroll
        for (int m = 8; m <= 32; m <<= 1) {
            a0 += __shfl_xor(a0, m, 64);
            a1 += __shfl_xor(a1, m, 64);
            a2 += __shfl_xor(a2, m, 64);
            a3 += __shfl_xor(a3, m, 64);
            a4 += __shfl_xor(a4, m, 64);
            a5 += __shfl_xor(a5, m, 64);
            a6 += __shfl_xor(a6, m, 64);
            a7 += __shfl_xor(a7, m, 64);
        }
        if (g == 0) {
            float c = (float)(end - beg);
            float inv = 1.0f / fmaxf(c, 1.0f);
            float4 r0, r1;
            r0.x = a0 * inv; r0.y = a1 * inv; r0.z = a2 * inv; r0.w = a3 * inv;
            r1.x = a4 * inv; r1.y = a5 * inv; r1.z = a6 * inv; r1.w = a7 * inv;
            sA[nd * XS + 2 * p] = r0;       // lanes p=0..7: stride 32B -> conflict-free
            sA[nd * XS + 2 * p + 1] = r1;
        }
    }
    __syncthreads();

    // ---- Phase 3: register-tile matmul + BN + ReLU (proven r8 structure) ----
    int dq = tid & 15;
    int nq = tid >> 4;
    float4 acc0 = {0.f, 0.f, 0.f, 0.f};
    float4 acc1 = {0.f, 0.f, 0.f, 0.f};
    float4 acc2 = {0.f, 0.f, 0.f, 0.f};
    float4 acc3 = {0.f, 0.f, 0.f, 0.f};

    int arow = nq * 4 * XS;
#pragma unroll 4
    for (int kg = 0; kg < 16; ++kg) {
        float4 wl0 = sWl[(kg * 4 + 0) * 16 + dq];
        float4 wl1 = sWl[(kg * 4 + 1) * 16 + dq];
        float4 wl2 = sWl[(kg * 4 + 2) * 16 + dq];
        float4 wl3 = sWl[(kg * 4 + 3) * 16 + dq];
        float4 wr0 = sWr[(kg * 4 + 0) * 16 + dq];
        float4 wr1 = sWr[(kg * 4 + 1) * 16 + dq];
        float4 wr2 = sWr[(kg * 4 + 2) * 16 + dq];
        float4 wr3 = sWr[(kg * 4 + 3) * 16 + dq];
        float4 a0 = sA[arow + 0 * XS + kg];
        float4 a1 = sA[arow + 1 * XS + kg];
        float4 a2 = sA[arow + 2 * XS + kg];
        float4 a3 = sA[arow + 3 * XS + kg];
        float4 h0 = sH[arow + 0 * XS + kg];
        float4 h1 = sH[arow + 1 * XS + kg];
        float4 h2 = sH[arow + 2 * XS + kg];
        float4 h3 = sH[arow + 3 * XS + kg];
#define ACC1(AC, AV, HV)                                                        \
        AC.x += AV.x * wl0.x + AV.y * wl1.x + AV.z * wl2.x + AV.w * wl3.x       \
              + HV.x * wr0.x + HV.y * wr1.x + HV.z * wr2.x + HV.w * wr3.x;      \
        AC.y += AV.x * wl0.y + AV.y * wl1.y + AV.z * wl2.y + AV.w * wl3.y       \
              + HV.x * wr0.y + HV.y * wr1.y + HV.z * wr2.y + HV.w * wr3.y;      \
        AC.z += AV.x * wl0.z + AV.y * wl1.z + AV.z * wl2.z + AV.w * wl3.z       \
              + HV.x * wr0.z + HV.y * wr1.z + HV.z * wr2.z + HV.w * wr3.z;      \
        AC.w += AV.x * wl0.w + AV.y * wl1.w + AV.z * wl2.w + AV.w * wl3.w       \
              + HV.x * wr0.w + HV.y * wr1.w + HV.z * wr2.w + HV.w * wr3.w;
        ACC1(acc0, a0, h0)
        ACC1(acc1, a1, h1)
        ACC1(acc2, a2, h2)
        ACC1(acc3, a3, h3)
#undef ACC1
    }

    float4 g4 = ((const float4*)bng)[dq];
    float4 v4 = ((const float4*)bnv)[dq];
    float4 be4 = ((const float4*)bnb)[dq];
    float4 rm4 = ((const float4*)bnm)[dq];
    float4 bi4 = ((const float4*)bl)[dq];
    float4 sc;
    sc.x = g4.x / sqrtf(v4.x + BN_EPS);
    sc.y = g4.y / sqrtf(v4.y + BN_EPS);
    sc.z = g4.z / sqrtf(v4.z + BN_EPS);
    sc.w = g4.w / sqrtf(v4.w + BN_EPS);

    float4* accp[4] = {&acc0, &acc1, &acc2, &acc3};
#pragma unroll
    for (int i = 0; i < 4; ++i) {
        int node = base + nq * 4 + i;
        if (node < n) {
            float4 a = *accp[i];
            float4 r;
            r.x = fmaxf((a.x + bi4.x - rm4.x) * sc.x + be4.x, 0.f);
            r.y = fmaxf((a.y + bi4.y - rm4.y) * sc.y + be4.y, 0.f);
            r.z = fmaxf((a.z + bi4.z - rm4.z) * sc.z + be4.z, 0.f);
            r.w = fmaxf((a.w + bi4.w - rm4.w) * sc.w + be4.w, 0.f);
            __half2 o01 = __float22half2_rn(make_float2(r.x, r.y));
            __half2 o23 = __float22half2_rn(make_float2(r.z, r.w));
            uint2 u;
            u.x = *(unsigned int*)&o01;
            u.y = *(unsigned int*)&o23;
            ((uint2*)(out16 + (size_t)node * DIM))[dq] = u;
        }
    }
}

// ---------------- global mean pool (batch sorted, fp16 features) ----------------

__global__ __launch_bounds__(256) void k_pool(const __half* __restrict__ h16,
                                              const int* __restrict__ batch,
                                              float* __restrict__ gsum,
                                              int* __restrict__ gcnt, int n) {
    int nw = gridDim.x * 4;
    int w = blockIdx.x * 4 + (threadIdx.x >> 6);
    int lane = threadIdx.x & 63;
    int chunk = (n + nw - 1) / nw;
    int s = w * chunk, e = min(s + chunk, n);
    if (s >= e) return;
    int cur = batch[s];
    float acc = 0.f;
    int cnt = 0;
    for (int i = s; i < e; ++i) {
        int g = batch[i];
        if (g != cur) {
            atomicAdd(&gsum[cur * DIM + lane], acc);
            if (lane == 0) atomicAdd(&gcnt[cur], cnt);
            acc = 0.f; cnt = 0; cur = g;
        }
        acc += __half2float(h16[(size_t)i * DIM + lane]);
        ++cnt;
    }
    atomicAdd(&gsum[cur * DIM + lane], acc);
    if (lane == 0) atomicAdd(&gcnt[cur], cnt);
}

// ---------------- classifier head ----------------

__global__ __launch_bounds__(256) void k_mlp(const float* __restrict__ gsum,
                                             const int* __restrict__ gcnt,
                                             const float* __restrict__ gattr,
                                             const float* __restrict__ W1,
                                             const float* __restrict__ b1,
                                             const float* __restrict__ W2,
                                             const float* __restrict__ b2,
                                             float* __restrict__ out) {
    __shared__ float emb[NGRAPH][DIM + GATTR];
    __shared__ float hid[NGRAPH][32];
    int tid = threadIdx.x;
    for (int i = tid; i < NGRAPH * DIM; i += 256) {
        int g = i >> 6, d = i & 63;
        float c = (float)gcnt[g];
        emb[g][d] = gsum[i] / fmaxf(c, 1.0f);
    }
    for (int i = tid; i < NGRAPH * GATTR; i += 256) {
        int g = i >> 2, d = i & 3;
        emb[g][DIM + d] = gattr[i];
    }
    __syncthreads();
    for (int t = tid; t < NGRAPH * 32; t += 256) {
        int g = t >> 5, j = t & 31;
        float a = b1[j];
        for (int k = 0; k < DIM + GATTR; ++k) a += emb[g][k] * W1[k * 32 + j];
        hid[g][j] = fmaxf(a, 0.f);
    }
    __syncthreads();
    {
        int g = tid >> 1, o = tid & 1;
        float a = b2[o];
        for (int k = 0; k < 32; ++k) a += hid[g][k] * W2[k * 2 + o];
        out[g * 2 + o] = a;
    }
}

extern "C" void kernel_launch(void* const* d_in, const int* in_sizes, int n_in,
                              void* d_out, int out_size, void* d_ws, size_t ws_size,
                              hipStream_t stream) {
    const float* x = (const float*)d_in[0];
    const int* ei = (const int*)d_in[1];
    const int* batch = (const int*)d_in[2];
    const float* gattr = (const float*)d_in[3];
    const int N = in_sizes[0] / DIM;
    const int E = in_sizes[1] / 2;
    const int* src = ei;
    const int* dst = ei + E;

    const float *Wl[3], *bl[3], *Wr[3], *bg[3], *bb[3], *bm[3], *bv[3];
    for (int l = 0; l < 3; ++l) {
        int base = 4 + l * 7;
        Wl[l] = (const float*)d_in[base + 0];
        bl[l] = (const float*)d_in[base + 1];
        Wr[l] = (const float*)d_in[base + 2];
        bg[l] = (const float*)d_in[base + 3];
        bb[l] = (const float*)d_in[base + 4];
        bm[l] = (const float*)d_in[base + 5];
        bv[l] = (const float*)d_in[base + 6];
    }
    const float* W1 = (const float*)d_in[25];
    const float* b1 = (const float*)d_in[26];
    const float* W2 = (const float*)d_in[27];
    const float* b2 = (const float*)d_in[28];

    char* ws = (char*)d_ws;
    size_t off = 0;
    auto alloc = [&](size_t bytes) -> char* {
        char* p = ws + off;
        off += (bytes + 255) & ~(size_t)255;
        return p;
    };
    const int nb = (E + SCHUNK - 1) / SCHUNK;              // binning blocks (306)
    const int nbuck = (N + BUCKET - 1) >> BUCKET_SHIFT;    // buckets (782)
    const int total_h = nbuck * nb;                        // hist entries (~239K)

    int* rowptr = (int*)alloc((size_t)(N + 1) * 4);
    int* col = (int*)alloc((size_t)E * 4);
    int* hist = (int*)alloc((size_t)total_h * 4);
    int2* pairs = (int2*)alloc((size_t)E * 8);
    __half* x16 = (__half*)alloc((size_t)N * DIM * 2);
    __half* h16a = (__half*)alloc((size_t)N * DIM * 2);
    __half* h16b = (__half*)alloc((size_t)N * DIM * 2);
    float* gsum = (float*)alloc((size_t)NGRAPH * DIM * 4);
    int* gcnt = (int*)alloc((size_t)NGRAPH * 4);
    int* partials = (int*)alloc(1024 * 4);
    (void)ws_size;

    const int tpb = 256;
    const int nscanH = (total_h + SCAN_CHUNK - 1) / SCAN_CHUNK;

    k_zero<<<(NGRAPH * DIM + tpb - 1) / tpb, tpb, 0, stream>>>(gsum, gcnt);
    k_cast<<<1024, tpb, 0, stream>>>((const float4*)x, (uint2*)x16, N * DIM / 4);

    k_bhist<<<nb, tpb, 0, stream>>>(dst, hist, E, nb, nbuck);
    k_gscan1<<<nscanH, tpb, 0, stream>>>(hist, hist, partials, total_h);
    k_gscan23<<<nscanH, tpb, 0, stream>>>(hist, partials, total_h);
    k_sbin<<<nb, tpb, 0, stream>>>(src, dst, hist, pairs, E, nb, nbuck);
    k_bsort<<<nbuck, tpb, 0, stream>>>(pairs, hist, rowptr, col, N, nb, nbuck, E);

    const __half* hin = x16;
    __half* houts[3] = {h16a, h16b, h16a};
    for (int l = 0; l < 3; ++l) {
        k_layer<<<(N + 63) / 64, 256, 0, stream>>>(hin, rowptr, col, Wl[l], bl[l], Wr[l],
                                                   bg[l], bb[l], bm[l], bv[l], houts[l], N);
        hin = houts[l];
    }

    k_pool<<<256, tpb, 0, stream>>>(hin, batch, gsum, gcnt, N);
    k_mlp<<<1, tpb, 0, stream>>>(gsum, gcnt, gattr, W1, b1, W2, b2, (float*)d_out);
}

// Round 15
// 450.816 us; speedup vs baseline: 1.4470x; 1.4470x over previous
//
#include <hip/hip_runtime.h>
#include <hip/hip_fp16.h>

#define DIM 64
#define NGRAPH 128
#define GATTR 4
#define BN_EPS 1e-5f
#define SCAN_CHUNK 4096   // 256 threads x 16 elems (generic scan)
#define SCHUNK 4096       // edges per binning block
#define BUCKET_SHIFT 7
#define BUCKET 128        // nodes per bucket; nbuck = ceil(N/128)
#define XS 17             // padded A/H row stride in float4 units (68 floats)

// ---------------- small zero (gsum/gcnt only) ----------------

__global__ __launch_bounds__(256) void k_zero(float* __restrict__ gsum,
                                              int* __restrict__ gcnt) {
    int i0 = blockIdx.x * 256 + threadIdx.x;
    if (i0 < NGRAPH * DIM) gsum[i0] = 0.f;
    if (i0 < NGRAPH) gcnt[i0] = 0;
}

// ---------------- f32 -> fp16 cast for input features ----------------

__global__ __launch_bounds__(256) void k_cast(const float4* __restrict__ x4,
                                              uint2* __restrict__ o, int n4) {
    int stride = gridDim.x * 256;
    for (int i = blockIdx.x * 256 + threadIdx.x; i < n4; i += stride) {
        float4 v = x4[i];
        __half2 a = __float22half2_rn(make_float2(v.x, v.y));
        __half2 b = __float22half2_rn(make_float2(v.z, v.w));
        uint2 u;
        u.x = *(unsigned int*)&a;
        u.y = *(unsigned int*)&b;
        o[i] = u;
    }
}

// ---------------- CSR build: deterministic rank-and-place (no global atomics) ----

__global__ __launch_bounds__(256) void k_bhist(const int* __restrict__ dst,
                                               int* __restrict__ hist,
                                               int E, int nb, int nbuck) {
    __shared__ int lb[1024];
    int tid = threadIdx.x, blk = blockIdx.x;
    int base = blk * SCHUNK;
    int cnt = min(SCHUNK, E - base);
    for (int i = tid; i < nbuck; i += 256) lb[i] = 0;
    __syncthreads();
    for (int i = tid; i < cnt; i += 256)
        atomicAdd(&lb[dst[base + i] >> BUCKET_SHIFT], 1);
    __syncthreads();
    for (int b = tid; b < nbuck; b += 256) hist[b * nb + blk] = lb[b];
}

__global__ __launch_bounds__(256) void k_gscan1(const int* __restrict__ in,
                                                int* __restrict__ out,
                                                int* __restrict__ partials, int n) {
    __shared__ int ws[256];
    int tid = threadIdx.x;
    int base = blockIdx.x * SCAN_CHUNK + tid * 16;
    int v[16];
    int s = 0;
#pragma unroll
    for (int i = 0; i < 16; ++i) {
        int idx = base + i;
        v[i] = (idx < n) ? in[idx] : 0;
        s += v[i];
    }
    ws[tid] = s;
    __syncthreads();
    for (int off = 1; off < 256; off <<= 1) {
        int t = (tid >= off) ? ws[tid - off] : 0;
        __syncthreads();
        ws[tid] += t;
        __syncthreads();
    }
    int excl = (tid == 0) ? 0 : ws[tid - 1];
    if (tid == 255) partials[blockIdx.x] = ws[255];
#pragma unroll
    for (int i = 0; i < 16; ++i) {
        int idx = base + i;
        if (idx < n) out[idx] = excl;
        excl += v[i];
    }
}

__global__ __launch_bounds__(256) void k_gscan23(int* __restrict__ data,
                                                 const int* __restrict__ partials,
                                                 int n) {
    __shared__ int soff;
    if (threadIdx.x == 0) {
        int s = 0;
        for (int j = 0; j < blockIdx.x; ++j) s += partials[j];
        soff = s;
    }
    __syncthreads();
    int off = soff;
    int base = blockIdx.x * SCAN_CHUNK;
    for (int i = threadIdx.x; i < SCAN_CHUNK; i += 256) {
        int idx = base + i;
        if (idx < n) data[idx] += off;
    }
}

// Deterministic binning. Global pairs packed as (src<<7)|dlocal (u32):
// src < 2^17, dlocal < 128 -> fits; halves pairs HBM traffic.
__global__ __launch_bounds__(256) void k_sbin(const int* __restrict__ src,
                                              const int* __restrict__ dst,
                                              const int* __restrict__ hist,
                                              unsigned int* __restrict__ pairs,
                                              int E, int nb, int nbuck) {
    __shared__ int lhist[1024];
    __shared__ int lofs[1024];
    __shared__ int lcur[1024];
    __shared__ int lgb[1024];
    __shared__ int ws[256];
    __shared__ int2 stage[SCHUNK];  // 32 KiB (LDS, keeps full dst for bucket id)
    int tid = threadIdx.x, blk = blockIdx.x;
    int base = blk * SCHUNK;
    int cnt = min(SCHUNK, E - base);

    for (int i = tid; i < nbuck; i += 256) lhist[i] = 0;
    __syncthreads();

    int2 mine[16];
    int nmine = 0;
    for (int i = tid; i < cnt; i += 256) {
        int s = src[base + i];
        int d = dst[base + i];
        mine[nmine++] = make_int2(s, d);
        atomicAdd(&lhist[d >> BUCKET_SHIFT], 1);
    }
    __syncthreads();

    {
        int b0 = tid * 4;
        int v0 = (b0 + 0 < nbuck) ? lhist[b0 + 0] : 0;
        int v1 = (b0 + 1 < nbuck) ? lhist[b0 + 1] : 0;
        int v2 = (b0 + 2 < nbuck) ? lhist[b0 + 2] : 0;
        int v3 = (b0 + 3 < nbuck) ? lhist[b0 + 3] : 0;
        int s = v0 + v1 + v2 + v3;
        ws[tid] = s;
        __syncthreads();
        for (int off = 1; off < 256; off <<= 1) {
            int t = (tid >= off) ? ws[tid - off] : 0;
            __syncthreads();
            ws[tid] += t;
            __syncthreads();
        }
        int excl = (tid == 0) ? 0 : ws[tid - 1];
        if (b0 + 0 < nbuck) lofs[b0 + 0] = excl;
        excl += v0;
        if (b0 + 1 < nbuck) lofs[b0 + 1] = excl;
        excl += v1;
        if (b0 + 2 < nbuck) lofs[b0 + 2] = excl;
        excl += v2;
        if (b0 + 3 < nbuck) lofs[b0 + 3] = excl;
    }
    __syncthreads();
    for (int b = tid; b < nbuck; b += 256) {
        lcur[b] = lofs[b];
        lgb[b] = hist[b * nb + blk];
    }
    __syncthreads();

    for (int j = 0; j < nmine; ++j) {
        int b = mine[j].y >> BUCKET_SHIFT;
        int pos = atomicAdd(&lcur[b], 1);
        stage[pos] = mine[j];
    }
    __syncthreads();

    for (int i = tid; i < cnt; i += 256) {
        int2 pr = stage[i];
        int b = pr.y >> BUCKET_SHIFT;
        unsigned int packed = ((unsigned int)pr.x << BUCKET_SHIFT) |
                              (unsigned int)(pr.y & (BUCKET - 1));
        pairs[lgb[b] + (i - lofs[b])] = packed;
    }
}

// Per-bucket counting sort -> col + rowptr (one block per bucket; LDS only).
__global__ __launch_bounds__(256) void k_bsort(const unsigned int* __restrict__ pairs,
                                               const int* __restrict__ hist,
                                               int* __restrict__ rowptr,
                                               int* __restrict__ col,
                                               int n, int nb, int nbuck, int E) {
    __shared__ int lcnt[BUCKET];
    __shared__ int lofs[BUCKET];
    int b = blockIdx.x;
    int tid = threadIdx.x;
    int cbase = hist[b * nb];
    int nxt = (b + 1 < nbuck) ? hist[(b + 1) * nb] : E;
    int ecnt = nxt - cbase;
    int node0 = b << BUCKET_SHIFT;
    int nn = min(BUCKET, n - node0);
    if (tid < BUCKET) lcnt[tid] = 0;
    __syncthreads();
    for (int i = tid; i < ecnt; i += 256)
        atomicAdd(&lcnt[pairs[cbase + i] & (BUCKET - 1)], 1);
    __syncthreads();
    int v = (tid < BUCKET) ? lcnt[tid] : 0;
    if (tid < BUCKET) lofs[tid] = v;
    __syncthreads();
    for (int off = 1; off < BUCKET; off <<= 1) {
        int t = (tid < BUCKET && tid >= off) ? lofs[tid - off] : 0;
        __syncthreads();
        if (tid < BUCKET) lofs[tid] += t;
        __syncthreads();
    }
    int excl = (tid < BUCKET) ? (lofs[tid] - v) : 0;
    __syncthreads();
    if (tid < BUCKET) lofs[tid] = excl;
    if (tid < nn) rowptr[node0 + tid] = cbase + excl;
    __syncthreads();
    for (int i = tid; i < ecnt; i += 256) {
        unsigned int pv = pairs[cbase + i];
        int p = cbase + atomicAdd(&lofs[pv & (BUCKET - 1)], 1);
        col[p] = (int)(pv >> BUCKET_SHIFT);
    }
    if (b == 0 && tid == 0) rowptr[n] = E;
}

// ---------------- mean aggregation (fp16 in, fp16 out) ----------------

__global__ __launch_bounds__(256) void k_agg(const __half* __restrict__ h16,
                                             const int* __restrict__ row_ptr,
                                             const int* __restrict__ col,
                                             __half* __restrict__ agg16, int n) {
    int wid = (blockIdx.x * blockDim.x + threadIdx.x) >> 6;
    if (wid >= n) return;
    int lane = threadIdx.x & 63;
    int g = lane >> 3;   // edge slot (8)
    int p = lane & 7;    // dim oct: dims 8p..8p+7
    int beg = row_ptr[wid], end = row_ptr[wid + 1];

    float a0 = 0.f, a1 = 0.f, a2 = 0.f, a3 = 0.f;
    float a4 = 0.f, a5 = 0.f, a6 = 0.f, a7 = 0.f;

#define ACCUM(V)                                                          \
    {                                                                     \
        const __half2* q = (const __half2*)&(V);                          \
        float2 f0 = __half22float2(q[0]);                                 \
        float2 f1 = __half22float2(q[1]);                                 \
        float2 f2 = __half22float2(q[2]);                                 \
        float2 f3 = __half22float2(q[3]);                                 \
        a0 += f0.x; a1 += f0.y; a2 += f1.x; a3 += f1.y;                   \
        a4 += f2.x; a5 += f2.y; a6 += f3.x; a7 += f3.y;                   \
    }

    int j = beg + g;
    for (; j + 8 < end; j += 16) {
        int s0 = col[j];
        int s1 = col[j + 8];
        uint4 v0 = ((const uint4*)(h16 + (size_t)s0 * DIM))[p];
        uint4 v1 = ((const uint4*)(h16 + (size_t)s1 * DIM))[p];
        ACCUM(v0)
        ACCUM(v1)
    }
    if (j < end) {
        int s0 = col[j];
        uint4 v0 = ((const uint4*)(h16 + (size_t)s0 * DIM))[p];
        ACCUM(v0)
    }
#undef ACCUM

#pragma unroll
    for (int m = 8; m <= 32; m <<= 1) {
        a0 += __shfl_xor(a0, m, 64);
        a1 += __shfl_xor(a1, m, 64);
        a2 += __shfl_xor(a2, m, 64);
        a3 += __shfl_xor(a3, m, 64);
        a4 += __shfl_xor(a4, m, 64);
        a5 += __shfl_xor(a5, m, 64);
        a6 += __shfl_xor(a6, m, 64);
        a7 += __shfl_xor(a7, m, 64);
    }

    if (g == 0) {
        float c = (float)(end - beg);
        float inv = 1.0f / fmaxf(c, 1.0f);
        __half2 h01 = __float22half2_rn(make_float2(a0 * inv, a1 * inv));
        __half2 h23 = __float22half2_rn(make_float2(a2 * inv, a3 * inv));
        __half2 h45 = __float22half2_rn(make_float2(a4 * inv, a5 * inv));
        __half2 h67 = __float22half2_rn(make_float2(a6 * inv, a7 * inv));
        uint4 u;
        u.x = *(unsigned int*)&h01;
        u.y = *(unsigned int*)&h23;
        u.z = *(unsigned int*)&h45;
        u.w = *(unsigned int*)&h67;
        ((uint4*)(agg16 + (size_t)wid * DIM))[p] = u;
    }
}

// ---------------- fused linear (agg@Wl + bl + h@Wr) + BN(eval) + ReLU ----------------
// A (fp16) and H (fp16) both unpacked to f32 in LDS; proven r8 4x4 register tile.

__global__ __launch_bounds__(256) void k_xform(const __half* __restrict__ agg16,
                                               const __half* __restrict__ h16,
                                               const float* __restrict__ Wl,
                                               const float* __restrict__ bl,
                                               const float* __restrict__ Wr,
                                               const float* __restrict__ bng,
                                               const float* __restrict__ bnb,
                                               const float* __restrict__ bnm,
                                               const float* __restrict__ bnv,
                                               __half* __restrict__ out16, int n) {
    __shared__ float4 sWl[64 * 16];
    __shared__ float4 sWr[64 * 16];
    __shared__ float4 sA[64 * XS];
    __shared__ float4 sH[64 * XS];
    int tid = threadIdx.x;
    int base = blockIdx.x * 64;
    int rows = min(64, n - base);

    const float4* Wl4 = (const float4*)Wl;
    const float4* Wr4 = (const float4*)Wr;
    const uint2* A2 = (const uint2*)(agg16 + (size_t)base * DIM);
    const uint2* H2 = (const uint2*)(h16 + (size_t)base * DIM);
    for (int i = tid; i < 1024; i += 256) {
        sWl[i] = Wl4[i];
        sWr[i] = Wr4[i];
        int row = i >> 4, c = i & 15;
        float4 va = {0.f, 0.f, 0.f, 0.f}, vh = {0.f, 0.f, 0.f, 0.f};
        if (row < rows) {
            uint2 ua = A2[i];
            const __half2* qa = (const __half2*)&ua;
            float2 alo = __half22float2(qa[0]);
            float2 ahi = __half22float2(qa[1]);
            va.x = alo.x; va.y = alo.y; va.z = ahi.x; va.w = ahi.y;
            uint2 u = H2[i];
            const __half2* q = (const __half2*)&u;
            float2 lo = __half22float2(q[0]);
            float2 hi = __half22float2(q[1]);
            vh.x = lo.x; vh.y = lo.y; vh.z = hi.x; vh.w = hi.y;
        }
        sA[row * XS + c] = va;
        sH[row * XS + c] = vh;
    }
    __syncthreads();

    int dq = tid & 15;
    int nq = tid >> 4;
    float4 acc0 = {0.f, 0.f, 0.f, 0.f};
    float4 acc1 = {0.f, 0.f, 0.f, 0.f};
    float4 acc2 = {0.f, 0.f, 0.f, 0.f};
    float4 acc3 = {0.f, 0.f, 0.f, 0.f};

    int arow = nq * 4 * XS;
#pragma unroll 4
    for (int kg = 0; kg < 16; ++kg) {
        float4 wl0 = sWl[(kg * 4 + 0) * 16 + dq];
        float4 wl1 = sWl[(kg * 4 + 1) * 16 + dq];
        float4 wl2 = sWl[(kg * 4 + 2) * 16 + dq];
        float4 wl3 = sWl[(kg * 4 + 3) * 16 + dq];
        float4 wr0 = sWr[(kg * 4 + 0) * 16 + dq];
        float4 wr1 = sWr[(kg * 4 + 1) * 16 + dq];
        float4 wr2 = sWr[(kg * 4 + 2) * 16 + dq];
        float4 wr3 = sWr[(kg * 4 + 3) * 16 + dq];
        float4 a0 = sA[arow + 0 * XS + kg];
        float4 a1 = sA[arow + 1 * XS + kg];
        float4 a2 = sA[arow + 2 * XS + kg];
        float4 a3 = sA[arow + 3 * XS + kg];
        float4 h0 = sH[arow + 0 * XS + kg];
        float4 h1 = sH[arow + 1 * XS + kg];
        float4 h2 = sH[arow + 2 * XS + kg];
        float4 h3 = sH[arow + 3 * XS + kg];
#define ACC1(AC, AV, HV)                                                        \
        AC.x += AV.x * wl0.x + AV.y * wl1.x + AV.z * wl2.x + AV.w * wl3.x       \
              + HV.x * wr0.x + HV.y * wr1.x + HV.z * wr2.x + HV.w * wr3.x;      \
        AC.y += AV.x * wl0.y + AV.y * wl1.y + AV.z * wl2.y + AV.w * wl3.y       \
              + HV.x * wr0.y + HV.y * wr1.y + HV.z * wr2.y + HV.w * wr3.y;      \
        AC.z += AV.x * wl0.z + AV.y * wl1.z + AV.z * wl2.z + AV.w * wl3.z       \
              + HV.x * wr0.z + HV.y * wr1.z + HV.z * wr2.z + HV.w * wr3.z;      \
        AC.w += AV.x * wl0.w + AV.y * wl1.w + AV.z * wl2.w + AV.w * wl3.w       \
              + HV.x * wr0.w + HV.y * wr1.w + HV.z * wr2.w + HV.w * wr3.w;
        ACC1(acc0, a0, h0)
        ACC1(acc1, a1, h1)
        ACC1(acc2, a2, h2)
        ACC1(acc3, a3, h3)
#undef ACC1
    }

    float4 g4 = ((const float4*)bng)[dq];
    float4 v4 = ((const float4*)bnv)[dq];
    float4 be4 = ((const float4*)bnb)[dq];
    float4 rm4 = ((const float4*)bnm)[dq];
    float4 bi4 = ((const float4*)bl)[dq];
    float4 sc;
    sc.x = g4.x / sqrtf(v4.x + BN_EPS);
    sc.y = g4.y / sqrtf(v4.y + BN_EPS);
    sc.z = g4.z / sqrtf(v4.z + BN_EPS);
    sc.w = g4.w / sqrtf(v4.w + BN_EPS);

    float4* accp[4] = {&acc0, &acc1, &acc2, &acc3};
#pragma unroll
    for (int i = 0; i < 4; ++i) {
        int node = base + nq * 4 + i;
        if (node < n) {
            float4 a = *accp[i];
            float4 r;
            r.x = fmaxf((a.x + bi4.x - rm4.x) * sc.x + be4.x, 0.f);
            r.y = fmaxf((a.y + bi4.y - rm4.y) * sc.y + be4.y, 0.f);
            r.z = fmaxf((a.z + bi4.z - rm4.z) * sc.z + be4.z, 0.f);
            r.w = fmaxf((a.w + bi4.w - rm4.w) * sc.w + be4.w, 0.f);
            __half2 o01 = __float22half2_rn(make_float2(r.x, r.y));
            __half2 o23 = __float22half2_rn(make_float2(r.z, r.w));
            uint2 u;
            u.x = *(unsigned int*)&o01;
            u.y = *(unsigned int*)&o23;
            ((uint2*)(out16 + (size_t)node * DIM))[dq] = u;
        }
    }
}

// ---------------- global mean pool (batch sorted, fp16 features) ----------------

__global__ __launch_bounds__(256) void k_pool(const __half* __restrict__ h16,
                                              const int* __restrict__ batch,
                                              float* __restrict__ gsum,
                                              int* __restrict__ gcnt, int n) {
    int nw = gridDim.x * 4;
    int w = blockIdx.x * 4 + (threadIdx.x >> 6);
    int lane = threadIdx.x & 63;
    int chunk = (n + nw - 1) / nw;
    int s = w * chunk, e = min(s + chunk, n);
    if (s >= e) return;
    int cur = batch[s];
    float acc = 0.f;
    int cnt = 0;
    for (int i = s; i < e; ++i) {
        int g = batch[i];
        if (g != cur) {
            atomicAdd(&gsum[cur * DIM + lane], acc);
            if (lane == 0) atomicAdd(&gcnt[cur], cnt);
            acc = 0.f; cnt = 0; cur = g;
        }
        acc += __half2float(h16[(size_t)i * DIM + lane]);
        ++cnt;
    }
    atomicAdd(&gsum[cur * DIM + lane], acc);
    if (lane == 0) atomicAdd(&gcnt[cur], cnt);
}

// ---------------- classifier head ----------------

__global__ __launch_bounds__(256) void k_mlp(const float* __restrict__ gsum,
                                             const int* __restrict__ gcnt,
                                             const float* __restrict__ gattr,
                                             const float* __restrict__ W1,
                                             const float* __restrict__ b1,
                                             const float* __restrict__ W2,
                                             const float* __restrict__ b2,
                                             float* __restrict__ out) {
    __shared__ float emb[NGRAPH][DIM + GATTR];
    __shared__ float hid[NGRAPH][32];
    int tid = threadIdx.x;
    for (int i = tid; i < NGRAPH * DIM; i += 256) {
        int g = i >> 6, d = i & 63;
        float c = (float)gcnt[g];
        emb[g][d] = gsum[i] / fmaxf(c, 1.0f);
    }
    for (int i = tid; i < NGRAPH * GATTR; i += 256) {
        int g = i >> 2, d = i & 3;
        emb[g][DIM + d] = gattr[i];
    }
    __syncthreads();
    for (int t = tid; t < NGRAPH * 32; t += 256) {
        int g = t >> 5, j = t & 31;
        float a = b1[j];
        for (int k = 0; k < DIM + GATTR; ++k) a += emb[g][k] * W1[k * 32 + j];
        hid[g][j] = fmaxf(a, 0.f);
    }
    __syncthreads();
    {
        int g = tid >> 1, o = tid & 1;
        float a = b2[o];
        for (int k = 0; k < 32; ++k) a += hid[g][k] * W2[k * 2 + o];
        out[g * 2 + o] = a;
    }
}

extern "C" void kernel_launch(void* const* d_in, const int* in_sizes, int n_in,
                              void* d_out, int out_size, void* d_ws, size_t ws_size,
                              hipStream_t stream) {
    const float* x = (const float*)d_in[0];
    const int* ei = (const int*)d_in[1];
    const int* batch = (const int*)d_in[2];
    const float* gattr = (const float*)d_in[3];
    const int N = in_sizes[0] / DIM;
    const int E = in_sizes[1] / 2;
    const int* src = ei;
    const int* dst = ei + E;

    const float *Wl[3], *bl[3], *Wr[3], *bg[3], *bb[3], *bm[3], *bv[3];
    for (int l = 0; l < 3; ++l) {
        int base = 4 + l * 7;
        Wl[l] = (const float*)d_in[base + 0];
        bl[l] = (const float*)d_in[base + 1];
        Wr[l] = (const float*)d_in[base + 2];
        bg[l] = (const float*)d_in[base + 3];
        bb[l] = (const float*)d_in[base + 4];
        bm[l] = (const float*)d_in[base + 5];
        bv[l] = (const float*)d_in[base + 6];
    }
    const float* W1 = (const float*)d_in[25];
    const float* b1 = (const float*)d_in[26];
    const float* W2 = (const float*)d_in[27];
    const float* b2 = (const float*)d_in[28];

    char* ws = (char*)d_ws;
    size_t off = 0;
    auto alloc = [&](size_t bytes) -> char* {
        char* p = ws + off;
        off += (bytes + 255) & ~(size_t)255;
        return p;
    };
    const int nb = (E + SCHUNK - 1) / SCHUNK;              // binning blocks (306)
    const int nbuck = (N + BUCKET - 1) >> BUCKET_SHIFT;    // buckets (782)
    const int total_h = nbuck * nb;                        // hist entries (~239K)

    int* rowptr = (int*)alloc((size_t)(N + 1) * 4);
    int* col = (int*)alloc((size_t)E * 4);
    int* hist = (int*)alloc((size_t)total_h * 4);
    unsigned int* pairs = (unsigned int*)alloc((size_t)E * 4);
    __half* agg16 = (__half*)alloc((size_t)N * DIM * 2);
    __half* x16 = (__half*)alloc((size_t)N * DIM * 2);
    __half* h16a = (__half*)alloc((size_t)N * DIM * 2);
    __half* h16b = (__half*)alloc((size_t)N * DIM * 2);
    float* gsum = (float*)alloc((size_t)NGRAPH * DIM * 4);
    int* gcnt = (int*)alloc((size_t)NGRAPH * 4);
    int* partials = (int*)alloc(1024 * 4);
    (void)ws_size;

    const int tpb = 256;
    const int nscanH = (total_h + SCAN_CHUNK - 1) / SCAN_CHUNK;

    k_zero<<<(NGRAPH * DIM + tpb - 1) / tpb, tpb, 0, stream>>>(gsum, gcnt);
    k_cast<<<1024, tpb, 0, stream>>>((const float4*)x, (uint2*)x16, N * DIM / 4);

    k_bhist<<<nb, tpb, 0, stream>>>(dst, hist, E, nb, nbuck);
    k_gscan1<<<nscanH, tpb, 0, stream>>>(hist, hist, partials, total_h);
    k_gscan23<<<nscanH, tpb, 0, stream>>>(hist, partials, total_h);
    k_sbin<<<nb, tpb, 0, stream>>>(src, dst, hist, pairs, E, nb, nbuck);
    k_bsort<<<nbuck, tpb, 0, stream>>>(pairs, hist, rowptr, col, N, nb, nbuck, E);

    const __half* hin = x16;
    __half* houts[3] = {h16a, h16b, h16a};
    for (int l = 0; l < 3; ++l) {
        k_agg<<<(N * 64 + tpb - 1) / tpb, tpb, 0, stream>>>(hin, rowptr, col, agg16, N);
        k_xform<<<(N + 63) / 64, 256, 0, stream>>>(agg16, hin, Wl[l], bl[l], Wr[l],
                                                   bg[l], bb[l], bm[l], bv[l], houts[l], N);
        hin = houts[l];
    }

    k_pool<<<256, tpb, 0, stream>>>(hin, batch, gsum, gcnt, N);
    k_mlp<<<1, tpb, 0, stream>>>(gsum, gcnt, gattr, W1, b1, W2, b2, (float*)d_out);
}